// Round 5
// baseline (1199.276 us; speedup 1.0000x reference)
//
#include <hip/hip_runtime.h>
#include <hip/hip_bf16.h>
#include <math.h>

#define SHIFT_ 4

typedef __attribute__((ext_vector_type(8))) short bh8;
typedef __attribute__((ext_vector_type(4))) short sh4;
typedef __attribute__((ext_vector_type(4))) float f4;
typedef __attribute__((ext_vector_type(8))) __bf16 bf8t;

static __device__ __forceinline__ f4 mfma16(bh8 a, bh8 b, f4 c){
  return __builtin_amdgcn_mfma_f32_16x16x32_bf16(
    __builtin_bit_cast(bf8t, a), __builtin_bit_cast(bf8t, b), c, 0, 0, 0);
}
static __device__ __forceinline__ unsigned short f2b(float f){
  unsigned u = __builtin_bit_cast(unsigned, f);
  u += 0x7fffu + ((u >> 16) & 1u);
  return (unsigned short)(u >> 16);
}
static __device__ __forceinline__ float b2f(unsigned short h){
  return __builtin_bit_cast(float, ((unsigned)h) << 16);
}

// ---------------- kernel 0: weights f32 -> bf16 (qw pre-scaled by d^-0.5) ---
__global__ __launch_bounds__(256) void prep_w(
    const float* __restrict__ qw, const float* __restrict__ kvw,
    const float* __restrict__ pw, const float* __restrict__ w1,
    const float* __restrict__ w2, unsigned short* __restrict__ wb){
  int i = blockIdx.x * 256 + threadIdx.x;   // 786432 total
  float v;
  if      (i < 65536)  v = qw[i] * 0.17677669529663687f;
  else if (i < 196608) v = kvw[i - 65536];
  else if (i < 262144) v = pw[i - 196608];
  else if (i < 524288) v = w1[i - 262144];
  else                 v = w2[i - 524288];
  wb[i] = f2b(v);
}

// ---------------- kernel 1: LN1 + roll(-4,-4) + window partition ------------
__global__ __launch_bounds__(256) void ln1_win(
    const float* __restrict__ x, const float* __restrict__ g1,
    const float* __restrict__ b1,
    unsigned short* __restrict__ q_in, unsigned short* __restrict__ kv_in){
  int rid  = blockIdx.x * 4 + (threadIdx.x >> 6);   // 0..262143
  int lane = threadIdx.x & 63;
  int d    = rid >> 17;
  int rem  = rid & 131071;          // w*64 + n
  int w = rem >> 6, n = rem & 63;
  int b = w >> 10, hb = (w >> 5) & 31, wbk = w & 31;
  int sh = (hb * 8 + (n >> 3) + SHIFT_) & 255;
  int sw = (wbk * 8 + (n & 7) + SHIFT_) & 255;
  const float* src = x + ((((size_t)(b * 2 + d)) * 256 + sh) * 256 + sw) * 256;
  float4 v = *(const float4*)(src + lane * 4);
  float s  = v.x + v.y + v.z + v.w;
  float ss = v.x * v.x + v.y * v.y + v.z * v.z + v.w * v.w;
  #pragma unroll
  for (int off = 1; off < 64; off <<= 1){ s += __shfl_xor(s, off); ss += __shfl_xor(ss, off); }
  float m    = s * (1.f / 256.f);
  float rstd = rsqrtf(ss * (1.f / 256.f) - m * m + 1e-5f);
  int c = lane * 4;
  float4 g  = *(const float4*)(g1 + c);
  float4 bb = *(const float4*)(b1 + c);
  sh4 o;
  o.x = (short)f2b((v.x - m) * rstd * g.x + bb.x);
  o.y = (short)f2b((v.y - m) * rstd * g.y + bb.y);
  o.z = (short)f2b((v.z - m) * rstd * g.z + bb.z);
  o.w = (short)f2b((v.w - m) * rstd * g.w + bb.w);
  unsigned short* dst = (d == 0 ? q_in : kv_in) + (size_t)rem * 256 + c;
  *(sh4*)dst = o;
}

// ---------------- generic GEMM: C = A(Mx256) @ W^T (+bias), 3 epilogues -----
template<int MODE>
__global__ __launch_bounds__(256) void gemm_bt(
    const unsigned short* __restrict__ A, const unsigned short* __restrict__ Wt,
    const float* __restrict__ bias, float bias_scale,
    unsigned short* __restrict__ outb, unsigned short* __restrict__ vt,
    float* __restrict__ outf, const unsigned short* __restrict__ qin,
    const float* __restrict__ xsrc){
  __shared__ unsigned short sA[128][72];
  __shared__ unsigned short sB[128][72];
  int m0 = blockIdx.x * 128, n0 = blockIdx.y * 128;
  int tid = threadIdx.x;
  int lane = tid & 63, wid = tid >> 6;
  int wm = wid >> 1, wn = wid & 1;
  int llo = lane & 15, lhi = lane >> 4;
  f4 acc[4][4];
  const f4 FZ = {0.f, 0.f, 0.f, 0.f};
  for (int i = 0; i < 4; i++) for (int j = 0; j < 4; j++) acc[i][j] = FZ;

  for (int k0 = 0; k0 < 256; k0 += 64){
    #pragma unroll
    for (int i = 0; i < 4; i++){
      int li = tid + i * 256;           // 0..1023
      int r = li >> 3, ck = li & 7;
      *(bh8*)&sA[r][ck * 8] = *(const bh8*)(A  + (size_t)(m0 + r) * 256 + k0 + ck * 8);
      *(bh8*)&sB[r][ck * 8] = *(const bh8*)(Wt + (size_t)(n0 + r) * 256 + k0 + ck * 8);
    }
    __syncthreads();
    #pragma unroll
    for (int ks = 0; ks < 2; ks++){
      bh8 a[4], b[4];
      #pragma unroll
      for (int mi = 0; mi < 4; mi++) a[mi] = *(const bh8*)&sA[wm * 64 + mi * 16 + llo][ks * 32 + lhi * 8];
      #pragma unroll
      for (int nj = 0; nj < 4; nj++) b[nj] = *(const bh8*)&sB[wn * 64 + nj * 16 + llo][ks * 32 + lhi * 8];
      #pragma unroll
      for (int mi = 0; mi < 4; mi++)
        #pragma unroll
        for (int nj = 0; nj < 4; nj++)
          acc[mi][nj] = mfma16(a[mi], b[nj], acc[mi][nj]);
    }
    __syncthreads();
  }
  #pragma unroll
  for (int mi = 0; mi < 4; mi++)
    for (int nj = 0; nj < 4; nj++){
      int col = n0 + wn * 64 + nj * 16 + llo;
      float bv = bias[col] * bias_scale;
      #pragma unroll
      for (int r = 0; r < 4; r++){
        int row = m0 + wm * 64 + mi * 16 + lhi * 4 + r;
        float val = acc[mi][nj][r] + bv;
        if (MODE == 0){
          outb[(size_t)row * 256 + col] = f2b(val);
        } else if (MODE == 1){
          if (col < 256) outb[(size_t)row * 256 + col] = f2b(val);
          else {
            int cv = col - 256, hd = cv >> 5, dd = cv & 31;
            int w = row >> 6, n = row & 63;
            vt[(((size_t)w * 8 + hd) * 32 + dd) * 64 + n] = f2b(val);
          }
        } else {
          int w = row >> 6, n = row & 63;
          int b = w >> 10, hb = (w >> 5) & 31, wbk = w & 31;
          int hh = (hb * 8 + (n >> 3) + SHIFT_) & 255;
          int ww = (wbk * 8 + (n & 7) + SHIFT_) & 255;
          float res = b2f(qin[(size_t)row * 256 + col]);
          float sc  = xsrc[((((size_t)(b * 2)) * 256 + hh) * 256 + ww) * 256 + col];
          outf[(((size_t)b * 256 + hh) * 256 + ww) * 256 + col] = val + res + sc;
        }
      }
    }
}

// ---------------- kernel 3: per (window, head) attention --------------------
__global__ __launch_bounds__(64) void attn_k(
    const unsigned short* __restrict__ q, const unsigned short* __restrict__ k,
    const unsigned short* __restrict__ vt, const float* __restrict__ mask,
    const float* __restrict__ bias_table, unsigned short* __restrict__ aout){
  __shared__ unsigned short sQ[64][40];
  __shared__ unsigned short sK[64][40];
  __shared__ unsigned short sVT[32][72];
  __shared__ unsigned short sP[64][72];
  __shared__ float sBias[225];
  int bid = blockIdx.x;
  int w = bid >> 3, hd = bid & 7;
  int lane = threadIdx.x;
  int llo = lane & 15, lhi = lane >> 4;
  for (int i = lane; i < 225; i += 64) sBias[i] = bias_table[i * 8 + hd];
  {
    const unsigned short* qp = q + ((size_t)w * 64 + lane) * 256 + hd * 32;
    const unsigned short* kp = k + ((size_t)w * 64 + lane) * 256 + hd * 32;
    #pragma unroll
    for (int c2 = 0; c2 < 4; c2++){
      *(bh8*)&sQ[lane][c2 * 8] = *(const bh8*)(qp + c2 * 8);
      *(bh8*)&sK[lane][c2 * 8] = *(const bh8*)(kp + c2 * 8);
    }
    const unsigned short* vp = vt + (((size_t)w * 8 + hd) * 32 + (lane >> 1)) * 64 + (lane & 1) * 32;
    #pragma unroll
    for (int c2 = 0; c2 < 4; c2++)
      *(bh8*)&sVT[lane >> 1][(lane & 1) * 32 + c2 * 8] = *(const bh8*)(vp + c2 * 8);
  }
  __syncthreads();
  const f4 FZ = {0.f, 0.f, 0.f, 0.f};
  f4 acc[4][4];
  {
    bh8 a[4], b[4];
    #pragma unroll
    for (int mi = 0; mi < 4; mi++) a[mi] = *(const bh8*)&sQ[mi * 16 + llo][lhi * 8];
    #pragma unroll
    for (int nj = 0; nj < 4; nj++) b[nj] = *(const bh8*)&sK[nj * 16 + llo][lhi * 8];
    #pragma unroll
    for (int mi = 0; mi < 4; mi++)
      #pragma unroll
      for (int nj = 0; nj < 4; nj++)
        acc[mi][nj] = mfma16(a[mi], b[nj], FZ);
  }
  const float* mrow = mask + (size_t)(w & 1023) * 4096;
  #pragma unroll
  for (int mi = 0; mi < 4; mi++){
    #pragma unroll
    for (int r = 0; r < 4; r++){
      int rr = mi * 16 + lhi * 4 + r;
      int yi = rr >> 3, xi = rr & 7;
      float sv[4]; float mx = -1e30f;
      #pragma unroll
      for (int nj = 0; nj < 4; nj++){
        int cc = nj * 16 + llo;
        int idx = (yi - (cc >> 3) + 7) * 15 + (xi - (cc & 7) + 7);
        sv[nj] = acc[mi][nj][r] + sBias[idx] + mrow[rr * 64 + cc];
        mx = fmaxf(mx, sv[nj]);
      }
      #pragma unroll
      for (int off = 1; off < 16; off <<= 1) mx = fmaxf(mx, __shfl_xor(mx, off));
      float sum = 0.f;
      #pragma unroll
      for (int nj = 0; nj < 4; nj++){ sv[nj] = __expf(sv[nj] - mx); sum += sv[nj]; }
      #pragma unroll
      for (int off = 1; off < 16; off <<= 1) sum += __shfl_xor(sum, off);
      float inv = 1.f / sum;
      #pragma unroll
      for (int nj = 0; nj < 4; nj++) sP[rr][nj * 16 + llo] = f2b(sv[nj] * inv);
    }
  }
  __syncthreads();
  f4 o[4][2];
  for (int mi = 0; mi < 4; mi++) for (int dj = 0; dj < 2; dj++) o[mi][dj] = FZ;
  #pragma unroll
  for (int ks = 0; ks < 2; ks++){
    bh8 pa[4], vb[2];
    #pragma unroll
    for (int mi = 0; mi < 4; mi++) pa[mi] = *(const bh8*)&sP[mi * 16 + llo][ks * 32 + lhi * 8];
    #pragma unroll
    for (int dj = 0; dj < 2; dj++) vb[dj] = *(const bh8*)&sVT[dj * 16 + llo][ks * 32 + lhi * 8];
    #pragma unroll
    for (int mi = 0; mi < 4; mi++)
      #pragma unroll
      for (int dj = 0; dj < 2; dj++)
        o[mi][dj] = mfma16(pa[mi], vb[dj], o[mi][dj]);
  }
  #pragma unroll
  for (int mi = 0; mi < 4; mi++)
    for (int dj = 0; dj < 2; dj++)
      for (int r = 0; r < 4; r++){
        int rr = mi * 16 + lhi * 4 + r, dd = dj * 16 + llo;
        aout[((size_t)w * 64 + rr) * 256 + hd * 32 + dd] = f2b(o[mi][dj][r]);
      }
}

// ---------------- kernel 4: LN2 -> bf16 xn (row-major) ----------------------
__global__ __launch_bounds__(256) void ln2_k(
    const float* __restrict__ x1, const float* __restrict__ g2,
    const float* __restrict__ b2, unsigned short* __restrict__ xn){
  int rid  = blockIdx.x * 4 + (threadIdx.x >> 6);   // 0..131071
  int lane = threadIdx.x & 63;
  const float* xr = x1 + (size_t)rid * 256;
  float4 v = *(const float4*)(xr + lane * 4);
  float s  = v.x + v.y + v.z + v.w;
  float ss = v.x * v.x + v.y * v.y + v.z * v.z + v.w * v.w;
  #pragma unroll
  for (int off = 1; off < 64; off <<= 1){ s += __shfl_xor(s, off); ss += __shfl_xor(ss, off); }
  float m    = s * (1.f / 256.f);
  float rstd = rsqrtf(ss * (1.f / 256.f) - m * m + 1e-5f);
  int c = lane * 4;
  float4 g  = *(const float4*)(g2 + c);
  float4 bb = *(const float4*)(b2 + c);
  sh4 o;
  o.x = (short)f2b((v.x - m) * rstd * g.x + bb.x);
  o.y = (short)f2b((v.y - m) * rstd * g.y + bb.y);
  o.z = (short)f2b((v.z - m) * rstd * g.z + bb.z);
  o.w = (short)f2b((v.w - m) * rstd * g.w + bb.w);
  *(sh4*)(xn + (size_t)rid * 256 + c) = o;
}

// ---------------- kernel 5: fused MLP (+residual), in-place on d_out --------
// v6: LN hoisted out; GEMM1 A-frags read from global xn (L2-hot per block);
// LDS = sH only (33.8KB) -> 4 blocks/CU = 16 waves/CU at unchanged per-wave
// MFMA density (16 MFMA/ks) and unchanged B-traffic. Compiler scheduling
// (manual prefetch queues proven no-op in r4).
__global__ __launch_bounds__(256, 4) void mlp_k(
    float* __restrict__ x1, const unsigned short* __restrict__ xn,
    const unsigned short* __restrict__ w1b, const float* __restrict__ bi1,
    const unsigned short* __restrict__ w2b, const float* __restrict__ bi2){
  __shared__ unsigned short sH[64][264];
  int rb = blockIdx.x * 64;
  int tid = threadIdx.x, lane = tid & 63, wid = tid >> 6;   // 4 waves
  int llo = lane & 15, lhi = lane >> 4;
  const f4 FZ = {0.f, 0.f, 0.f, 0.f};
  f4 acc2[4][4];
  for (int i = 0; i < 4; i++) for (int j = 0; j < 4; j++) acc2[i][j] = FZ;
  const unsigned short* xnt = xn  + (size_t)(rb + llo) * 256 + lhi * 8;
  const unsigned short* w1t = w1b + (size_t)(wid * 64 + llo) * 256 + lhi * 8;
  const unsigned short* w2t = w2b + (size_t)(wid * 64 + llo) * 1024 + lhi * 8;
  #pragma unroll
  for (int hc = 0; hc < 4; hc++){
    // ---- GEMM1: H_chunk = xn @ W1_chunk^T (A and B both from global/L2) ----
    f4 acc1[4][4];
    for (int i = 0; i < 4; i++) for (int j = 0; j < 4; j++) acc1[i][j] = FZ;
    const unsigned short* w1p = w1t + hc * 65536;   // += hc*256 rows * 256
    #pragma unroll
    for (int ks = 0; ks < 8; ks++){
      bh8 a[4], b[4];
      #pragma unroll
      for (int mi = 0; mi < 4; mi++) a[mi] = *(const bh8*)(xnt + mi * 4096 + ks * 32);
      #pragma unroll
      for (int nj = 0; nj < 4; nj++) b[nj] = *(const bh8*)(w1p + nj * 4096 + ks * 32);
      #pragma unroll
      for (int mi = 0; mi < 4; mi++)
        #pragma unroll
        for (int nj = 0; nj < 4; nj++)
          acc1[mi][nj] = mfma16(a[mi], b[nj], acc1[mi][nj]);
    }
    __syncthreads();   // prev GEMM2 done reading sH
    #pragma unroll
    for (int mi = 0; mi < 4; mi++)
      #pragma unroll
      for (int nj = 0; nj < 4; nj++){
        int oc = wid * 64 + nj * 16 + llo;
        float bv = bi1[hc * 256 + oc];
        #pragma unroll
        for (int r = 0; r < 4; r++){
          float hv = acc1[mi][nj][r] + bv;
          float u = hv * (1.5957691216f + 0.0713548162f * hv * hv);  // 2*0.79788456*(x+0.044715x^3)/x
          float gv = hv / (1.f + __expf(-u));
          sH[mi * 16 + lhi * 4 + r][oc] = f2b(gv);
        }
      }
    __syncthreads();
    // ---- GEMM2: out += gelu(H) @ W2_chunk^T (A from LDS, B from global) ----
    const unsigned short* w2p = w2t + hc * 256;
    #pragma unroll
    for (int ks = 0; ks < 8; ks++){
      bh8 a[4], c[4];
      #pragma unroll
      for (int mi = 0; mi < 4; mi++) a[mi] = *(const bh8*)&sH[mi * 16 + llo][ks * 32 + lhi * 8];
      #pragma unroll
      for (int nj = 0; nj < 4; nj++) c[nj] = *(const bh8*)(w2p + nj * 16384 + ks * 32);
      #pragma unroll
      for (int mi = 0; mi < 4; mi++)
        #pragma unroll
        for (int nj = 0; nj < 4; nj++)
          acc2[mi][nj] = mfma16(a[mi], c[nj], acc2[mi][nj]);
    }
  }
  #pragma unroll
  for (int mi = 0; mi < 4; mi++)
    #pragma unroll
    for (int nj = 0; nj < 4; nj++){
      int c2 = wid * 64 + nj * 16 + llo;
      float bv = bi2[c2];
      #pragma unroll
      for (int r = 0; r < 4; r++){
        size_t idx = ((size_t)rb + mi * 16 + lhi * 4 + r) * 256 + c2;
        x1[idx] += acc2[mi][nj][r] + bv;
      }
    }
}

extern "C" void kernel_launch(void* const* d_in, const int* in_sizes, int n_in,
                              void* d_out, int out_size, void* d_ws, size_t ws_size,
                              hipStream_t stream){
  const float* x          = (const float*)d_in[0];
  const float* mask       = (const float*)d_in[1];
  const float* g1         = (const float*)d_in[2];
  const float* b1         = (const float*)d_in[3];
  const float* qw         = (const float*)d_in[4];
  const float* qb         = (const float*)d_in[5];
  const float* kvw        = (const float*)d_in[6];
  const float* kvb        = (const float*)d_in[7];
  const float* pw         = (const float*)d_in[8];
  const float* pb         = (const float*)d_in[9];
  const float* bias_table = (const float*)d_in[10];
  const float* g2         = (const float*)d_in[11];
  const float* b2         = (const float*)d_in[12];
  const float* w1         = (const float*)d_in[13];
  const float* bi1        = (const float*)d_in[14];
  const float* w2         = (const float*)d_in[15];
  const float* bi2        = (const float*)d_in[16];
  float* out = (float*)d_out;
  char* ws = (char*)d_ws;
  const long long SEG = 67108864LL;   // 2048*64*256 bf16 bytes
  unsigned short* q_in  = (unsigned short*)(ws);
  unsigned short* kv_in = (unsigned short*)(ws + SEG);
  unsigned short* qbuf  = (unsigned short*)(ws + 2 * SEG);
  unsigned short* kbuf  = (unsigned short*)(ws + 3 * SEG);
  unsigned short* vtb   = (unsigned short*)(ws + 4 * SEG);
  unsigned short* wb    = (unsigned short*)(ws + 5 * SEG);
  unsigned short* aoutb = kv_in;      // kv_in dead after kv GEMM -> alias
  unsigned short* xn    = qbuf;       // qbuf dead after attn_k -> alias

  prep_w<<<3072, 256, 0, stream>>>(qw, kvw, pw, w1, w2, wb);
  ln1_win<<<65536, 256, 0, stream>>>(x, g1, b1, q_in, kv_in);
  gemm_bt<0><<<dim3(1024, 2), 256, 0, stream>>>(q_in, wb, qb, 0.17677669529663687f,
                                                qbuf, nullptr, nullptr, nullptr, nullptr);
  gemm_bt<1><<<dim3(1024, 4), 256, 0, stream>>>(kv_in, wb + 65536, kvb, 1.0f,
                                                kbuf, vtb, nullptr, nullptr, nullptr);
  attn_k<<<16384, 64, 0, stream>>>(qbuf, kbuf, vtb, mask, bias_table, aoutb);
  gemm_bt<2><<<dim3(1024, 2), 256, 0, stream>>>(aoutb, wb + 196608, pb, 1.0f,
                                                nullptr, nullptr, out, q_in, x);
  ln2_k<<<32768, 256, 0, stream>>>(out, g2, b2, xn);
  mlp_k<<<2048, 256, 0, stream>>>(out, xn, wb + 262144, bi1, wb + 524288, bi2);
}

// Round 6
// 955.247 us; speedup vs baseline: 1.2555x; 1.2555x over previous
//
#include <hip/hip_runtime.h>
#include <hip/hip_bf16.h>
#include <math.h>

#define SHIFT_ 4

typedef __attribute__((ext_vector_type(8))) short bh8;
typedef __attribute__((ext_vector_type(4))) short sh4;
typedef __attribute__((ext_vector_type(4))) float f4;
typedef __attribute__((ext_vector_type(8))) __bf16 bf8t;

static __device__ __forceinline__ f4 mfma16(bh8 a, bh8 b, f4 c){
  return __builtin_amdgcn_mfma_f32_16x16x32_bf16(
    __builtin_bit_cast(bf8t, a), __builtin_bit_cast(bf8t, b), c, 0, 0, 0);
}
static __device__ __forceinline__ unsigned short f2b(float f){
  unsigned u = __builtin_bit_cast(unsigned, f);
  u += 0x7fffu + ((u >> 16) & 1u);
  return (unsigned short)(u >> 16);
}
static __device__ __forceinline__ float b2f(unsigned short h){
  return __builtin_bit_cast(float, ((unsigned)h) << 16);
}
static __device__ __forceinline__ unsigned cvt_pk_bf16(float lo, float hi){
  unsigned r;
  asm("v_cvt_pk_bf16_f32 %0, %1, %2" : "=v"(r) : "v"(lo), "v"(hi));
  return r;
}

// ---------------- kernel 0: weights f32 -> bf16 (qw pre-scaled by d^-0.5) ---
__global__ __launch_bounds__(256) void prep_w(
    const float* __restrict__ qw, const float* __restrict__ kvw,
    const float* __restrict__ pw, const float* __restrict__ w1,
    const float* __restrict__ w2, unsigned short* __restrict__ wb){
  int i = blockIdx.x * 256 + threadIdx.x;   // 786432 total
  float v;
  if      (i < 65536)  v = qw[i] * 0.17677669529663687f;
  else if (i < 196608) v = kvw[i - 65536];
  else if (i < 262144) v = pw[i - 196608];
  else if (i < 524288) v = w1[i - 262144];
  else                 v = w2[i - 524288];
  wb[i] = f2b(v);
}

// ---------------- kernel 1: LN1 + roll(-4,-4) + window partition ------------
__global__ __launch_bounds__(256) void ln1_win(
    const float* __restrict__ x, const float* __restrict__ g1,
    const float* __restrict__ b1,
    unsigned short* __restrict__ q_in, unsigned short* __restrict__ kv_in){
  int rid  = blockIdx.x * 4 + (threadIdx.x >> 6);   // 0..262143
  int lane = threadIdx.x & 63;
  int d    = rid >> 17;
  int rem  = rid & 131071;          // w*64 + n
  int w = rem >> 6, n = rem & 63;
  int b = w >> 10, hb = (w >> 5) & 31, wbk = w & 31;
  int sh = (hb * 8 + (n >> 3) + SHIFT_) & 255;
  int sw = (wbk * 8 + (n & 7) + SHIFT_) & 255;
  const float* src = x + ((((size_t)(b * 2 + d)) * 256 + sh) * 256 + sw) * 256;
  float4 v = *(const float4*)(src + lane * 4);
  float s  = v.x + v.y + v.z + v.w;
  float ss = v.x * v.x + v.y * v.y + v.z * v.z + v.w * v.w;
  #pragma unroll
  for (int off = 1; off < 64; off <<= 1){ s += __shfl_xor(s, off); ss += __shfl_xor(ss, off); }
  float m    = s * (1.f / 256.f);
  float rstd = rsqrtf(ss * (1.f / 256.f) - m * m + 1e-5f);
  int c = lane * 4;
  float4 g  = *(const float4*)(g1 + c);
  float4 bb = *(const float4*)(b1 + c);
  sh4 o;
  o.x = (short)f2b((v.x - m) * rstd * g.x + bb.x);
  o.y = (short)f2b((v.y - m) * rstd * g.y + bb.y);
  o.z = (short)f2b((v.z - m) * rstd * g.z + bb.z);
  o.w = (short)f2b((v.w - m) * rstd * g.w + bb.w);
  unsigned short* dst = (d == 0 ? q_in : kv_in) + (size_t)rem * 256 + c;
  *(sh4*)dst = o;
}

// ---------------- generic GEMM: C = A(Mx256) @ W^T (+bias), 3 epilogues -----
template<int MODE>
__global__ __launch_bounds__(256) void gemm_bt(
    const unsigned short* __restrict__ A, const unsigned short* __restrict__ Wt,
    const float* __restrict__ bias, float bias_scale,
    unsigned short* __restrict__ outb, unsigned short* __restrict__ vt,
    float* __restrict__ outf, const unsigned short* __restrict__ qin,
    const float* __restrict__ xsrc){
  __shared__ unsigned short sA[128][72];
  __shared__ unsigned short sB[128][72];
  int m0 = blockIdx.x * 128, n0 = blockIdx.y * 128;
  int tid = threadIdx.x;
  int lane = tid & 63, wid = tid >> 6;
  int wm = wid >> 1, wn = wid & 1;
  int llo = lane & 15, lhi = lane >> 4;
  f4 acc[4][4];
  const f4 FZ = {0.f, 0.f, 0.f, 0.f};
  for (int i = 0; i < 4; i++) for (int j = 0; j < 4; j++) acc[i][j] = FZ;

  for (int k0 = 0; k0 < 256; k0 += 64){
    #pragma unroll
    for (int i = 0; i < 4; i++){
      int li = tid + i * 256;           // 0..1023
      int r = li >> 3, ck = li & 7;
      *(bh8*)&sA[r][ck * 8] = *(const bh8*)(A  + (size_t)(m0 + r) * 256 + k0 + ck * 8);
      *(bh8*)&sB[r][ck * 8] = *(const bh8*)(Wt + (size_t)(n0 + r) * 256 + k0 + ck * 8);
    }
    __syncthreads();
    #pragma unroll
    for (int ks = 0; ks < 2; ks++){
      bh8 a[4], b[4];
      #pragma unroll
      for (int mi = 0; mi < 4; mi++) a[mi] = *(const bh8*)&sA[wm * 64 + mi * 16 + llo][ks * 32 + lhi * 8];
      #pragma unroll
      for (int nj = 0; nj < 4; nj++) b[nj] = *(const bh8*)&sB[wn * 64 + nj * 16 + llo][ks * 32 + lhi * 8];
      #pragma unroll
      for (int mi = 0; mi < 4; mi++)
        #pragma unroll
        for (int nj = 0; nj < 4; nj++)
          acc[mi][nj] = mfma16(a[mi], b[nj], acc[mi][nj]);
    }
    __syncthreads();
  }
  #pragma unroll
  for (int mi = 0; mi < 4; mi++)
    for (int nj = 0; nj < 4; nj++){
      int col = n0 + wn * 64 + nj * 16 + llo;
      float bv = bias[col] * bias_scale;
      #pragma unroll
      for (int r = 0; r < 4; r++){
        int row = m0 + wm * 64 + mi * 16 + lhi * 4 + r;
        float val = acc[mi][nj][r] + bv;
        if (MODE == 0){
          outb[(size_t)row * 256 + col] = f2b(val);
        } else if (MODE == 1){
          if (col < 256) outb[(size_t)row * 256 + col] = f2b(val);
          else {
            int cv = col - 256, hd = cv >> 5, dd = cv & 31;
            int w = row >> 6, n = row & 63;
            vt[(((size_t)w * 8 + hd) * 32 + dd) * 64 + n] = f2b(val);
          }
        } else {
          int w = row >> 6, n = row & 63;
          int b = w >> 10, hb = (w >> 5) & 31, wbk = w & 31;
          int hh = (hb * 8 + (n >> 3) + SHIFT_) & 255;
          int ww = (wbk * 8 + (n & 7) + SHIFT_) & 255;
          float res = b2f(qin[(size_t)row * 256 + col]);
          float sc  = xsrc[((((size_t)(b * 2)) * 256 + hh) * 256 + ww) * 256 + col];
          outf[(((size_t)b * 256 + hh) * 256 + ww) * 256 + col] = val + res + sc;
        }
      }
    }
}

// ---------------- kernel 3: per (window, head) attention --------------------
__global__ __launch_bounds__(64) void attn_k(
    const unsigned short* __restrict__ q, const unsigned short* __restrict__ k,
    const unsigned short* __restrict__ vt, const float* __restrict__ mask,
    const float* __restrict__ bias_table, unsigned short* __restrict__ aout){
  __shared__ unsigned short sQ[64][40];
  __shared__ unsigned short sK[64][40];
  __shared__ unsigned short sVT[32][72];
  __shared__ unsigned short sP[64][72];
  __shared__ float sBias[225];
  int bid = blockIdx.x;
  int w = bid >> 3, hd = bid & 7;
  int lane = threadIdx.x;
  int llo = lane & 15, lhi = lane >> 4;
  for (int i = lane; i < 225; i += 64) sBias[i] = bias_table[i * 8 + hd];
  {
    const unsigned short* qp = q + ((size_t)w * 64 + lane) * 256 + hd * 32;
    const unsigned short* kp = k + ((size_t)w * 64 + lane) * 256 + hd * 32;
    #pragma unroll
    for (int c2 = 0; c2 < 4; c2++){
      *(bh8*)&sQ[lane][c2 * 8] = *(const bh8*)(qp + c2 * 8);
      *(bh8*)&sK[lane][c2 * 8] = *(const bh8*)(kp + c2 * 8);
    }
    const unsigned short* vp = vt + (((size_t)w * 8 + hd) * 32 + (lane >> 1)) * 64 + (lane & 1) * 32;
    #pragma unroll
    for (int c2 = 0; c2 < 4; c2++)
      *(bh8*)&sVT[lane >> 1][(lane & 1) * 32 + c2 * 8] = *(const bh8*)(vp + c2 * 8);
  }
  __syncthreads();
  const f4 FZ = {0.f, 0.f, 0.f, 0.f};
  f4 acc[4][4];
  {
    bh8 a[4], b[4];
    #pragma unroll
    for (int mi = 0; mi < 4; mi++) a[mi] = *(const bh8*)&sQ[mi * 16 + llo][lhi * 8];
    #pragma unroll
    for (int nj = 0; nj < 4; nj++) b[nj] = *(const bh8*)&sK[nj * 16 + llo][lhi * 8];
    #pragma unroll
    for (int mi = 0; mi < 4; mi++)
      #pragma unroll
      for (int nj = 0; nj < 4; nj++)
        acc[mi][nj] = mfma16(a[mi], b[nj], FZ);
  }
  const float* mrow = mask + (size_t)(w & 1023) * 4096;
  #pragma unroll
  for (int mi = 0; mi < 4; mi++){
    #pragma unroll
    for (int r = 0; r < 4; r++){
      int rr = mi * 16 + lhi * 4 + r;
      int yi = rr >> 3, xi = rr & 7;
      float sv[4]; float mx = -1e30f;
      #pragma unroll
      for (int nj = 0; nj < 4; nj++){
        int cc = nj * 16 + llo;
        int idx = (yi - (cc >> 3) + 7) * 15 + (xi - (cc & 7) + 7);
        sv[nj] = acc[mi][nj][r] + sBias[idx] + mrow[rr * 64 + cc];
        mx = fmaxf(mx, sv[nj]);
      }
      #pragma unroll
      for (int off = 1; off < 16; off <<= 1) mx = fmaxf(mx, __shfl_xor(mx, off));
      float sum = 0.f;
      #pragma unroll
      for (int nj = 0; nj < 4; nj++){ sv[nj] = __expf(sv[nj] - mx); sum += sv[nj]; }
      #pragma unroll
      for (int off = 1; off < 16; off <<= 1) sum += __shfl_xor(sum, off);
      float inv = __builtin_amdgcn_rcpf(sum);
      #pragma unroll
      for (int nj = 0; nj < 4; nj++) sP[rr][nj * 16 + llo] = f2b(sv[nj] * inv);
    }
  }
  __syncthreads();
  f4 o[4][2];
  for (int mi = 0; mi < 4; mi++) for (int dj = 0; dj < 2; dj++) o[mi][dj] = FZ;
  #pragma unroll
  for (int ks = 0; ks < 2; ks++){
    bh8 pa[4], vb[2];
    #pragma unroll
    for (int mi = 0; mi < 4; mi++) pa[mi] = *(const bh8*)&sP[mi * 16 + llo][ks * 32 + lhi * 8];
    #pragma unroll
    for (int dj = 0; dj < 2; dj++) vb[dj] = *(const bh8*)&sVT[dj * 16 + llo][ks * 32 + lhi * 8];
    #pragma unroll
    for (int mi = 0; mi < 4; mi++)
      #pragma unroll
      for (int dj = 0; dj < 2; dj++)
        o[mi][dj] = mfma16(pa[mi], vb[dj], o[mi][dj]);
  }
  #pragma unroll
  for (int mi = 0; mi < 4; mi++)
    for (int dj = 0; dj < 2; dj++)
      for (int r = 0; r < 4; r++){
        int rr = mi * 16 + lhi * 4 + r, dd = dj * 16 + llo;
        aout[((size_t)w * 64 + rr) * 256 + hd * 32 + dd] = f2b(o[mi][dj][r]);
      }
}

// ---------------- kernel 5: fused LN2 + MLP (+residual), in-place on d_out --
// v7: hidden chunk 128 -> sX(33.8K)+sH(17.4K)=51.2KB -> 3 blocks/CU (3 phase
// streams). GEMM1 operand-swapped: mfma(W1frag, Xfrag) so each lane holds 4
// consecutive-hidden outputs for one row -> epilogue = float4 bias +
// 2x v_cvt_pk_bf16_f32 + ds_write_b64. rcp instead of exact div in gelu.
__global__ __launch_bounds__(256, 3) void mlp_k(
    float* __restrict__ x1, const float* __restrict__ g2,
    const float* __restrict__ b2, const unsigned short* __restrict__ w1b,
    const float* __restrict__ bi1, const unsigned short* __restrict__ w2b,
    const float* __restrict__ bi2){
  __shared__ unsigned short sX[64][264];
  __shared__ unsigned short sH[64][136];
  int rb = blockIdx.x * 64;
  int tid = threadIdx.x, lane = tid & 63, wid = tid >> 6;   // 4 waves
  int llo = lane & 15, lhi = lane >> 4;
  for (int rr = wid; rr < 64; rr += 4){
    const float* xr = x1 + ((size_t)rb + rr) * 256;
    float4 v = *(const float4*)(xr + lane * 4);
    float s  = v.x + v.y + v.z + v.w;
    float ss = v.x * v.x + v.y * v.y + v.z * v.z + v.w * v.w;
    #pragma unroll
    for (int off = 1; off < 64; off <<= 1){ s += __shfl_xor(s, off); ss += __shfl_xor(ss, off); }
    float m    = s * (1.f / 256.f);
    float rstd = rsqrtf(ss * (1.f / 256.f) - m * m + 1e-5f);
    int c = lane * 4;
    float4 g  = *(const float4*)(g2 + c);
    float4 bb = *(const float4*)(b2 + c);
    sh4 o;
    o.x = (short)f2b((v.x - m) * rstd * g.x + bb.x);
    o.y = (short)f2b((v.y - m) * rstd * g.y + bb.y);
    o.z = (short)f2b((v.z - m) * rstd * g.z + bb.z);
    o.w = (short)f2b((v.w - m) * rstd * g.w + bb.w);
    *(sh4*)&sX[rr][c] = o;
  }
  __syncthreads();
  const f4 FZ = {0.f, 0.f, 0.f, 0.f};
  f4 acc2[4][4];
  for (int i = 0; i < 4; i++) for (int j = 0; j < 4; j++) acc2[i][j] = FZ;
  // GEMM1 B-frag rows = hidden (wave covers 32 hidden cols of the 128-chunk)
  const unsigned short* w1t = w1b + (size_t)(wid * 32 + llo) * 256 + lhi * 8;
  // GEMM2 B-frag rows = output cols (wave covers 64 of 256)
  const unsigned short* w2t = w2b + (size_t)(wid * 64 + llo) * 1024 + lhi * 8;
  for (int hc = 0; hc < 8; hc++){
    // ---- GEMM1 (swapped): acc1[nj][mi], hidden idx = lhi*4+r ----
    f4 acc1[2][4];
    for (int i = 0; i < 2; i++) for (int j = 0; j < 4; j++) acc1[i][j] = FZ;
    const unsigned short* w1p = w1t + (size_t)hc * 32768;   // hc*128 rows * 256
    #pragma unroll
    for (int ks = 0; ks < 8; ks++){
      bh8 a[4], b[2];
      #pragma unroll
      for (int mi = 0; mi < 4; mi++) a[mi] = *(const bh8*)&sX[mi * 16 + llo][ks * 32 + lhi * 8];
      #pragma unroll
      for (int nj = 0; nj < 2; nj++) b[nj] = *(const bh8*)(w1p + nj * 4096 + ks * 32);
      #pragma unroll
      for (int nj = 0; nj < 2; nj++)
        #pragma unroll
        for (int mi = 0; mi < 4; mi++)
          acc1[nj][mi] = mfma16(b[nj], a[mi], acc1[nj][mi]);
    }
    __syncthreads();   // prev GEMM2 done reading sH
    #pragma unroll
    for (int nj = 0; nj < 2; nj++){
      int ocb = wid * 32 + nj * 16 + lhi * 4;      // 4 consecutive hidden
      float4 bv = *(const float4*)(bi1 + hc * 128 + ocb);
      #pragma unroll
      for (int mi = 0; mi < 4; mi++){
        float gv[4];
        float hv0 = acc1[nj][mi][0] + bv.x;
        float hv1 = acc1[nj][mi][1] + bv.y;
        float hv2 = acc1[nj][mi][2] + bv.z;
        float hv3 = acc1[nj][mi][3] + bv.w;
        #pragma unroll
        for (int r = 0; r < 4; r++){
          float hv = (r==0?hv0:r==1?hv1:r==2?hv2:hv3);
          float u = hv * (1.5957691216f + 0.0713548162f * hv * hv);
          gv[r] = hv * __builtin_amdgcn_rcpf(1.f + __expf(-u));
        }
        uint2 p;
        p.x = cvt_pk_bf16(gv[0], gv[1]);
        p.y = cvt_pk_bf16(gv[2], gv[3]);
        *(uint2*)&sH[mi * 16 + llo][ocb] = p;
      }
    }
    __syncthreads();
    // ---- GEMM2: out += gelu(H) @ W2_chunk^T ----
    const unsigned short* w2p = w2t + hc * 128;
    #pragma unroll
    for (int ks = 0; ks < 4; ks++){
      bh8 a[4], c[4];
      #pragma unroll
      for (int mi = 0; mi < 4; mi++) a[mi] = *(const bh8*)&sH[mi * 16 + llo][ks * 32 + lhi * 8];
      #pragma unroll
      for (int nj = 0; nj < 4; nj++) c[nj] = *(const bh8*)(w2p + nj * 16384 + ks * 32);
      #pragma unroll
      for (int mi = 0; mi < 4; mi++)
        #pragma unroll
        for (int nj = 0; nj < 4; nj++)
          acc2[mi][nj] = mfma16(a[mi], c[nj], acc2[mi][nj]);
    }
  }
  #pragma unroll
  for (int mi = 0; mi < 4; mi++)
    #pragma unroll
    for (int nj = 0; nj < 4; nj++){
      int c2 = wid * 64 + nj * 16 + llo;
      float bv = bi2[c2];
      #pragma unroll
      for (int r = 0; r < 4; r++){
        size_t idx = ((size_t)rb + mi * 16 + lhi * 4 + r) * 256 + c2;
        x1[idx] += acc2[mi][nj][r] + bv;
      }
    }
}

extern "C" void kernel_launch(void* const* d_in, const int* in_sizes, int n_in,
                              void* d_out, int out_size, void* d_ws, size_t ws_size,
                              hipStream_t stream){
  const float* x          = (const float*)d_in[0];
  const float* mask       = (const float*)d_in[1];
  const float* g1         = (const float*)d_in[2];
  const float* b1         = (const float*)d_in[3];
  const float* qw         = (const float*)d_in[4];
  const float* qb         = (const float*)d_in[5];
  const float* kvw        = (const float*)d_in[6];
  const float* kvb        = (const float*)d_in[7];
  const float* pw         = (const float*)d_in[8];
  const float* pb         = (const float*)d_in[9];
  const float* bias_table = (const float*)d_in[10];
  const float* g2         = (const float*)d_in[11];
  const float* b2         = (const float*)d_in[12];
  const float* w1         = (const float*)d_in[13];
  const float* bi1        = (const float*)d_in[14];
  const float* w2         = (const float*)d_in[15];
  const float* bi2        = (const float*)d_in[16];
  float* out = (float*)d_out;
  char* ws = (char*)d_ws;
  const long long SEG = 67108864LL;   // 2048*64*256 bf16 bytes
  unsigned short* q_in  = (unsigned short*)(ws);
  unsigned short* kv_in = (unsigned short*)(ws + SEG);
  unsigned short* qbuf  = (unsigned short*)(ws + 2 * SEG);
  unsigned short* kbuf  = (unsigned short*)(ws + 3 * SEG);
  unsigned short* vtb   = (unsigned short*)(ws + 4 * SEG);
  unsigned short* wb    = (unsigned short*)(ws + 5 * SEG);
  unsigned short* aoutb = kv_in;      // kv_in dead after kv GEMM -> alias

  prep_w<<<3072, 256, 0, stream>>>(qw, kvw, pw, w1, w2, wb);
  ln1_win<<<65536, 256, 0, stream>>>(x, g1, b1, q_in, kv_in);
  gemm_bt<0><<<dim3(1024, 2), 256, 0, stream>>>(q_in, wb, qb, 0.17677669529663687f,
                                                qbuf, nullptr, nullptr, nullptr, nullptr);
  gemm_bt<1><<<dim3(1024, 4), 256, 0, stream>>>(kv_in, wb + 65536, kvb, 1.0f,
                                                kbuf, vtb, nullptr, nullptr, nullptr);
  attn_k<<<16384, 64, 0, stream>>>(qbuf, kbuf, vtb, mask, bias_table, aoutb);
  gemm_bt<2><<<dim3(1024, 2), 256, 0, stream>>>(aoutb, wb + 196608, pb, 1.0f,
                                                nullptr, nullptr, out, q_in, x);
  mlp_k<<<2048, 256, 0, stream>>>(out, g2, b2, wb + 262144, bi1, wb + 524288, bi2);
}